// Round 8
// baseline (982.490 us; speedup 1.0000x reference)
//
#include <hip/hip_runtime.h>
#include <stdint.h>

#define D_HID 1024
#define BATCH 8
#define TLEN 4096
#define M_ROWS (BATCH*TLEN)   // 32768
#define CHUNK 128
#define NCHUNK (TLEN/CHUNK)   // 32

typedef __attribute__((ext_vector_type(8))) short s8v;
typedef __attribute__((ext_vector_type(4))) float f4v;

__device__ __forceinline__ ushort f2bf(float x){
  uint32_t u = __builtin_bit_cast(uint32_t, x);
  uint32_t r = u + 0x7fffu + ((u>>16)&1u);
  return (ushort)(r>>16);
}

// async global->LDS, 16B per lane (m97 pattern; dest must be lane-linear)
__device__ __forceinline__ void gload_lds16(const ushort* g, ushort* l){
  __builtin_amdgcn_global_load_lds(
      (const __attribute__((address_space(1))) uint32_t*)g,
      (__attribute__((address_space(3))) uint32_t*)l, 16, 0, 0);
}

// ---- convert fp32 -> bf16 (vectorized) ----
__global__ void k_cvt(const float* __restrict__ in, ushort* __restrict__ out, int n4){
  int i = blockIdx.x*blockDim.x + threadIdx.x;
  if (i >= n4) return;
  float4 v = ((const float4*)in)[i];
  ushort4 o;
  o.x = f2bf(v.x); o.y = f2bf(v.y); o.z = f2bf(v.z); o.w = f2bf(v.w);
  ((ushort4*)out)[i] = o;
}

// ---- transpose 4x 1024x1024 fp32 (K,N) -> bf16 (N,K); blockIdx.z picks weight ----
__global__ void k_tr4(const float* __restrict__ s0, const float* __restrict__ s1,
                      const float* __restrict__ s2, const float* __restrict__ s3,
                      ushort* __restrict__ d0, ushort* __restrict__ d1,
                      ushort* __restrict__ d2, ushort* __restrict__ d3){
  const float* src; ushort* dst; int dstride;
  switch (blockIdx.z){
    case 0:  src=s0; dst=d0; dstride=1024; break;   // W_a   -> WcatT rows 0..1023
    case 1:  src=s1; dst=d1; dstride=1024; break;   // W_b   -> WcatT rows 1024..2047
    case 2:  src=s2; dst=d2; dstride=2048; break;   // W_y   -> W2T k part 0..1023
    default: src=s3; dst=d3; dstride=2048; break;   // W_skip-> W2T k-offset 1024
  }
  __shared__ float t[32][33];
  int k0 = blockIdx.x*32, n0 = blockIdx.y*32;
  int tx = threadIdx.x, ty = threadIdx.y; // 32 x 8
  #pragma unroll
  for (int i=0;i<4;i++) t[ty+i*8][tx] = src[(size_t)(k0+ty+i*8)*D_HID + n0+tx];
  __syncthreads();
  #pragma unroll
  for (int i=0;i<4;i++) dst[(size_t)(n0+ty+i*8)*dstride + k0+tx] = f2bf(t[tx][ty+i*8]);
}

// ---- bf16 MFMA GEMM, 128x128 tile, BK=32, 4 waves, 4x4 16x16 frags/wave ----
// MODE 1: A = xb (stride 1024), B = WcatT [2048][1024]; epilogue: col<1024 -> sigmoid(+bias)->out0(a)
//         else -> out1(b).  K=1024.
// MODE 2: A: k<1024 -> A0 (gelu_h bf16), k>=1024 -> A1 (xb); B = W2T [1024][2048]; out0 = y. K=2048.
template<int MODE>
__global__ __launch_bounds__(256) void k_gemm(
    const ushort* __restrict__ A0, const ushort* __restrict__ A1,
    const ushort* __restrict__ Bt, int ldb, int K,
    const float* __restrict__ bias,
    float* __restrict__ out0, float* __restrict__ out1)
{
  __shared__ ushort lA[128*32];
  __shared__ ushort lB[128*32];
  int bn = blockIdx.x, bm = blockIdx.y;
  int tid = threadIdx.x;
  int wid = tid>>6, lane = tid&63;
  int wm = wid>>1, wn = wid&1;
  int lr = lane&15, lk = lane>>4;
  f4v acc[4][4] = {};

  for (int kk=0; kk<K; kk+=32){
    const ushort* Asrc;
    if (MODE==2 && kk>=1024) Asrc = A1 + (size_t)bm*128*1024 + (kk-1024);
    else                     Asrc = A0 + (size_t)bm*128*1024 + kk;
    const ushort* Bsrc = Bt + (size_t)bn*128*ldb + kk;
    __syncthreads();   // prior-iter LDS reads complete before overwrite
    #pragma unroll
    for (int i=0;i<2;i++){
      int lin = i*256 + tid;
      int row = lin>>2, kq = lin&3;
      gload_lds16(Asrc + (size_t)row*1024 + kq*8, lA + (size_t)lin*8);
      gload_lds16(Bsrc + (size_t)row*ldb  + kq*8, lB + (size_t)lin*8);
    }
    __syncthreads();   // compiler drains vmcnt(0) before s_barrier
    s8v af[4], bfr[4];
    const s8v* A8 = (const s8v*)lA;
    const s8v* B8 = (const s8v*)lB;
    #pragma unroll
    for (int m=0;m<4;m++) af[m] = A8[(wm*64+m*16+lr)*4 + lk];
    #pragma unroll
    for (int n=0;n<4;n++) bfr[n] = B8[(wn*64+n*16+lr)*4 + lk];
    #pragma unroll
    for (int m=0;m<4;m++)
      #pragma unroll
      for (int n=0;n<4;n++)
        acc[m][n] = __builtin_amdgcn_mfma_f32_16x16x32_bf16(af[m], bfr[n], acc[m][n], 0,0,0);
  }

  int baseRow = bm*128 + wm*64;
  int baseCol = bn*128 + wn*64;
  #pragma unroll
  for (int m=0;m<4;m++){
    #pragma unroll
    for (int n=0;n<4;n++){
      int col = baseCol + n*16 + lr;
      #pragma unroll
      for (int r=0;r<4;r++){
        int row = baseRow + m*16 + lk*4 + r;
        float v = acc[m][n][r];
        if (MODE==1){
          if (col < 1024){
            float s = v + bias[col];
            s = 1.f/(1.f + __expf(-s));
            out0[(size_t)row*1024 + col] = s;
          } else {
            out1[(size_t)row*1024 + (col-1024)] = v;
          }
        } else {
          out0[(size_t)row*1024 + col] = v;
        }
      }
    }
  }
}

// ---- scan pass A: per-chunk monoid state (Ap = prod a, Bc = chunk-applied b) ----
__global__ void k_scanA(const float* __restrict__ aw, const float* __restrict__ bw,
                        float* __restrict__ stA, float* __restrict__ stB){
  int d = blockIdx.z*256 + threadIdx.x;
  int c = blockIdx.x, b = blockIdx.y;
  size_t base = ((size_t)(b*TLEN + c*CHUNK))*D_HID + d;
  float Ap = 1.f, Bc = 0.f;
  #pragma unroll 4
  for (int t=0;t<CHUNK;t++){
    float a  = aw[base + (size_t)t*D_HID];
    float bb = bw[base + (size_t)t*D_HID];
    Ap *= a;
    Bc = fmaf(a, Bc, bb);
  }
  size_t si = ((size_t)(b*NCHUNK + c))*D_HID + d;
  stA[si] = Ap; stB[si] = Bc;
}

// ---- scan pass B: serial scan over chunk states, emit per-chunk starting h ----
__global__ void k_scanB(const float* __restrict__ h0, const float* __restrict__ stA,
                        const float* __restrict__ stB, float* __restrict__ hstart){
  int idx = blockIdx.x*256 + threadIdx.x; // b*1024 + d
  float h = h0[idx];
  int b = idx>>10, d = idx&1023;
  for (int c=0;c<NCHUNK;c++){
    size_t si = ((size_t)(b*NCHUNK+c))*D_HID + d;
    hstart[si] = h;
    h = fmaf(stA[si], h, stB[si]);
  }
}

// ---- scan pass C: apply, write next_h (fp32 out) and gelu(h) (bf16 ws) ----
// NOTE: bw and hout ALIAS (bw == out_h region): each thread reads bw[i] then
// writes hout[i] at the same index — sequential per-thread, no __restrict__.
__global__ void k_scanC(const float* __restrict__ aw, const float* bw,
                        const float* __restrict__ hstart,
                        float* hout, ushort* __restrict__ gws){
  int d = blockIdx.z*256 + threadIdx.x;
  int c = blockIdx.x, b = blockIdx.y;
  size_t base = ((size_t)(b*TLEN + c*CHUNK))*D_HID + d;
  float h = hstart[((size_t)(b*NCHUNK+c))*D_HID + d];
  #pragma unroll 4
  for (int t=0;t<CHUNK;t++){
    float a  = aw[base + (size_t)t*D_HID];
    float bb = bw[base + (size_t)t*D_HID];
    h = fmaf(a, h, bb);
    hout[base + (size_t)t*D_HID] = h;
    // gelu(x) = x * sigmoid(2*0.79788456*(x + 0.044715 x^3))  (tanh approx == jax default)
    float u = 1.5957691216057308f*(h + 0.044715f*h*h*h);
    float g = h * (1.f/(1.f + __expf(-u)));
    gws[base + (size_t)t*D_HID] = f2bf(g);
  }
}

extern "C" void kernel_launch(void* const* d_in, const int* in_sizes, int n_in,
                              void* d_out, int out_size, void* d_ws, size_t ws_size,
                              hipStream_t stream){
  const float* x      = (const float*)d_in[0];
  const float* h0     = (const float*)d_in[1];
  const float* W_a    = (const float*)d_in[2];
  const float* b_a    = (const float*)d_in[3];
  const float* W_b    = (const float*)d_in[4];
  const float* W_y    = (const float*)d_in[5];
  const float* W_skip = (const float*)d_in[6];
  float* out_h = (float*)d_out;
  float* out_y = out_h + (size_t)M_ROWS*D_HID;

  // Alias the big fp32 intermediates onto d_out (legal: bw is last read by
  // scanC exactly where it writes next_h; aw is last read by scanC, before
  // GEMM2 overwrites out_y). Workspace need: 139 MiB.
  float* aw = out_y;   // 'a' gate values, 128 MiB
  float* bw = out_h;   // 'b' values, 128 MiB

  char* ws = (char*)d_ws;
  ushort* xb    = (ushort*)(ws);                          // 64 MiB
  ushort* gws   = (ushort*)(ws + ((size_t)64<<20));       // 64 MiB
  ushort* WcatT = (ushort*)(ws + ((size_t)128<<20));      // 4 MiB  [2048][1024]
  ushort* W2T   = (ushort*)(ws + ((size_t)132<<20));      // 4 MiB  [1024][2048]
  float*  stA   = (float*)(ws + ((size_t)136<<20));       // 1 MiB
  float*  stB   = (float*)(ws + ((size_t)137<<20));       // 1 MiB
  float*  hstart= (float*)(ws + ((size_t)138<<20));       // 1 MiB

  // x -> bf16
  k_cvt<<<dim3(M_ROWS*D_HID/4/256), 256, 0, stream>>>(x, xb, M_ROWS*D_HID/4);
  // weights -> transposed bf16 (one fused launch; z picks the weight)
  k_tr4<<<dim3(32,32,4), dim3(32,8), 0, stream>>>(
      W_a, W_b, W_y, W_skip,
      WcatT, WcatT + (size_t)1024*1024, W2T, W2T + 1024);
  // GEMM1: [a|b] = x @ [W_a|W_b], sigmoid fused for a
  k_gemm<1><<<dim3(16,256), 256, 0, stream>>>(xb, nullptr, WcatT, 1024, 1024, b_a, aw, bw);
  // chunked scan
  k_scanA<<<dim3(NCHUNK,BATCH,4), 256, 0, stream>>>(aw, bw, stA, stB);
  k_scanB<<<dim3(32), 256, 0, stream>>>(h0, stA, stB, hstart);
  k_scanC<<<dim3(NCHUNK,BATCH,4), 256, 0, stream>>>(aw, bw, hstart, out_h, gws);
  // GEMM2: y = gelu(h) @ W_y + x @ W_skip   (K=2048 concat)
  k_gemm<2><<<dim3(8,256), 256, 0, stream>>>(gws, xb, W2T, 2048, 2048, nullptr, out_y, nullptr);
}

// Round 10
// 869.101 us; speedup vs baseline: 1.1305x; 1.1305x over previous
//
#include <hip/hip_runtime.h>
#include <stdint.h>

#define D_HID 1024
#define BATCH 8
#define TLEN 4096
#define M_ROWS (BATCH*TLEN)   // 32768
#define CHUNK 128
#define NCHUNK (TLEN/CHUNK)   // 32

typedef __attribute__((ext_vector_type(8))) short s8v;
typedef __attribute__((ext_vector_type(4))) float f4v;

__device__ __forceinline__ ushort f2bf(float x){
  uint32_t u = __builtin_bit_cast(uint32_t, x);
  uint32_t r = u + 0x7fffu + ((u>>16)&1u);
  return (ushort)(r>>16);
}

// async global->LDS, 16B per lane (m97 pattern; dest must be lane-linear)
__device__ __forceinline__ void gload_lds16(const ushort* g, ushort* l){
  __builtin_amdgcn_global_load_lds(
      (const __attribute__((address_space(1))) uint32_t*)g,
      (__attribute__((address_space(3))) uint32_t*)l, 16, 0, 0);
}

// ---- convert fp32 -> bf16 (vectorized) ----
__global__ void k_cvt(const float* __restrict__ in, ushort* __restrict__ out, int n4){
  int i = blockIdx.x*blockDim.x + threadIdx.x;
  if (i >= n4) return;
  float4 v = ((const float4*)in)[i];
  ushort4 o;
  o.x = f2bf(v.x); o.y = f2bf(v.y); o.z = f2bf(v.z); o.w = f2bf(v.w);
  ((ushort4*)out)[i] = o;
}

// ---- transpose 4x 1024x1024 fp32 (K,N) -> bf16 (N,K); blockIdx.z picks weight ----
__global__ void k_tr4(const float* __restrict__ s0, const float* __restrict__ s1,
                      const float* __restrict__ s2, const float* __restrict__ s3,
                      ushort* __restrict__ d0, ushort* __restrict__ d1,
                      ushort* __restrict__ d2, ushort* __restrict__ d3){
  const float* src; ushort* dst; int dstride;
  switch (blockIdx.z){
    case 0:  src=s0; dst=d0; dstride=1024; break;
    case 1:  src=s1; dst=d1; dstride=1024; break;
    case 2:  src=s2; dst=d2; dstride=2048; break;
    default: src=s3; dst=d3; dstride=2048; break;
  }
  __shared__ float t[32][33];
  int k0 = blockIdx.x*32, n0 = blockIdx.y*32;
  int tx = threadIdx.x, ty = threadIdx.y; // 32 x 8
  #pragma unroll
  for (int i=0;i<4;i++) t[ty+i*8][tx] = src[(size_t)(k0+ty+i*8)*D_HID + n0+tx];
  __syncthreads();
  #pragma unroll
  for (int i=0;i<4;i++) dst[(size_t)(n0+ty+i*8)*dstride + k0+tx] = f2bf(t[tx][ty+i*8]);
}

// ---- 256x256 bf16 MFMA GEMM, BK=64, 8 waves (2Mx4N), 4-phase counted-vmcnt pipeline ----
// LDS: [2 slots][2 khalves][256 rows][32 k] for A and B (64 KiB each, 128 KiB dynamic).
// Swizzle: colbyte ^= ((row>>1)&3)<<4  (involution; per-8-lane b128 groups cover all 32 banks).
// Stage order per phase (next tile): p1=B-kh0, p2=A-kh0, p3=B-kh1, p4=A-kh1.
// vmcnt(4) at p2/p4-end forces exactly the half-tiles the next-consuming phase needs.
// MODE 1: A=xb, B=WcatT[2048][1024], K=1024; bn<4 -> sigmoid(v+bias)->out0, else out1.
// MODE 2: A concat (k<1024 gws, else xb), B=W2T[1024][2048], K=2048 -> out0.
template<int MODE>
__global__ __launch_bounds__(512, 2) void k_gemm(
    const ushort* __restrict__ A0, const ushort* __restrict__ A1,
    const ushort* __restrict__ Bt, int ldb, int K,
    const float* __restrict__ bias,
    float* __restrict__ out0, float* __restrict__ out1)
{
  extern __shared__ ushort lds_u16[];
  ushort* lA = lds_u16;          // 2*16384
  ushort* lB = lds_u16 + 32768;  // 2*16384
  int bn = blockIdx.x, bm = blockIdx.y;
  int tid = threadIdx.x;
  int wid = tid>>6, lane = tid&63;
  int wm = wid>>2, wn = wid&3;           // 2 x 4 waves
  int lr = lane&15, lk = lane>>4;
  f4v acc[8][4] = {};
  s8v a[8];
  const int NT = K>>6;

  // stage one 16B piece: unit u: 0=B-kh0 1=A-kh0 2=B-kh1 3=A-kh1; round j in {0,1}; dest slot
  auto stage = [&](int T1, int u, int j, int dslot){
    int kh  = u>>1;
    int idx = j*512 + tid;                 // 0..1023 ; 16B each = 16 KiB half-tile
    int row = idx>>2;                      // 0..255
    int cb  = (idx&3)<<4;                  // byte col in 64B row
    int sc  = cb ^ (((row>>1)&3)<<4);      // inverse-swizzled source col
    int kg  = T1*64 + kh*32 + (sc>>1);
    const ushort* g;
    ushort* l;
    if (u & 1) { // A
      const ushort* Ab = A0; int kk = kg;
      if (MODE==2 && kg >= 1024) { Ab = A1; kk = kg - 1024; }
      g = Ab + (size_t)(bm*256 + row)*1024 + kk;
      l = lA + dslot*16384 + kh*8192 + idx*8;
    } else {     // B
      g = Bt + (size_t)(bn*256 + row)*ldb + kg;
      l = lB + dslot*16384 + kh*8192 + idx*8;
    }
    gload_lds16(g, l);
  };
  auto rdA = [&](int m, int ks, int sl)->s8v{
    int row = wm*128 + m*16 + lr;
    int sc  = (lk<<4) ^ (((row>>1)&3)<<4);
    return *(const s8v*)(lA + sl*16384 + ks*8192 + row*32 + (sc>>1));
  };
  auto rdB = [&](int n, int ks, int sl)->s8v{
    int row = wn*64 + n*16 + lr;
    int sc  = (lk<<4) ^ (((row>>1)&3)<<4);
    return *(const s8v*)(lB + sl*16384 + ks*8192 + row*32 + (sc>>1));
  };

#define PHASE(KS, NH, UST, DOA, ISEND) do {                                   \
    if (DOA) { _Pragma("unroll")                                              \
      for (int m_=0; m_<8; ++m_) a[m_] = rdA(m_, KS, s); }                    \
    s8v b0 = rdB((NH)*2,   KS, s);                                            \
    s8v b1 = rdB((NH)*2+1, KS, s);                                            \
    if (T+1 < NT) { stage(T+1, UST, 0, d); stage(T+1, UST, 1, d); }           \
    __builtin_amdgcn_s_barrier();                                             \
    asm volatile("s_waitcnt lgkmcnt(0)" ::: "memory");                        \
    __builtin_amdgcn_s_setprio(1);                                            \
    _Pragma("unroll")                                                         \
    for (int m_=0; m_<8; ++m_) {                                              \
      acc[m_][(NH)*2]   = __builtin_amdgcn_mfma_f32_16x16x32_bf16(a[m_], b0, acc[m_][(NH)*2],   0,0,0); \
      acc[m_][(NH)*2+1] = __builtin_amdgcn_mfma_f32_16x16x32_bf16(a[m_], b1, acc[m_][(NH)*2+1], 0,0,0); \
    }                                                                         \
    __builtin_amdgcn_s_setprio(0);                                            \
    if (ISEND) {                                                              \
      if (T+1 < NT) asm volatile("s_waitcnt vmcnt(4)" ::: "memory");          \
      else          asm volatile("s_waitcnt vmcnt(0)" ::: "memory");          \
    }                                                                         \
    __builtin_amdgcn_s_barrier();                                             \
  } while(0)

  // prologue: stage tile 0 (B-kh0, A-kh0, B-kh1, A-kh1) into slot 0
  #pragma unroll
  for (int u=0; u<4; ++u){ stage(0,u,0,0); stage(0,u,1,0); }
  asm volatile("s_waitcnt vmcnt(4)" ::: "memory");  // forces B-kh0 + A-kh0
  __builtin_amdgcn_s_barrier();

  for (int T=0; T<NT; ++T){
    int s = T&1, d = s^1;
    PHASE(0,0, 0, true , false);
    PHASE(0,1, 1, false, true );
    PHASE(1,0, 2, true , false);
    PHASE(1,1, 3, false, true );
  }
#undef PHASE

  int baseRow = bm*256 + wm*128;
  int baseCol = bn*256 + wn*64;
  #pragma unroll
  for (int m=0;m<8;m++){
    #pragma unroll
    for (int n=0;n<4;n++){
      int col = baseCol + n*16 + lr;
      #pragma unroll
      for (int r=0;r<4;r++){
        int row = baseRow + m*16 + lk*4 + r;
        float v = acc[m][n][r];
        if (MODE==1){
          if (col < 1024){
            float sg = v + bias[col];
            sg = 1.f/(1.f + __expf(-sg));
            out0[(size_t)row*1024 + col] = sg;
          } else {
            out1[(size_t)row*1024 + (col-1024)] = v;
          }
        } else {
          out0[(size_t)row*1024 + col] = v;
        }
      }
    }
  }
}

// ---- scan pass A: per-chunk monoid state ----
__global__ void k_scanA(const float* __restrict__ aw, const float* __restrict__ bw,
                        float* __restrict__ stA, float* __restrict__ stB){
  int d = blockIdx.z*256 + threadIdx.x;
  int c = blockIdx.x, b = blockIdx.y;
  size_t base = ((size_t)(b*TLEN + c*CHUNK))*D_HID + d;
  float Ap = 1.f, Bc = 0.f;
  #pragma unroll 4
  for (int t=0;t<CHUNK;t++){
    float a  = aw[base + (size_t)t*D_HID];
    float bb = bw[base + (size_t)t*D_HID];
    Ap *= a;
    Bc = fmaf(a, Bc, bb);
  }
  size_t si = ((size_t)(b*NCHUNK + c))*D_HID + d;
  stA[si] = Ap; stB[si] = Bc;
}

// ---- scan pass B: serial scan over chunk states ----
__global__ void k_scanB(const float* __restrict__ h0, const float* __restrict__ stA,
                        const float* __restrict__ stB, float* __restrict__ hstart){
  int idx = blockIdx.x*256 + threadIdx.x; // b*1024 + d
  float h = h0[idx];
  int b = idx>>10, d = idx&1023;
  for (int c=0;c<NCHUNK;c++){
    size_t si = ((size_t)(b*NCHUNK+c))*D_HID + d;
    hstart[si] = h;
    h = fmaf(stA[si], h, stB[si]);
  }
}

// ---- scan pass C: apply, write next_h (fp32 out) and gelu(h) (bf16 ws) ----
// bw aliases hout: read-before-write at same index per thread.
__global__ void k_scanC(const float* __restrict__ aw, const float* bw,
                        const float* __restrict__ hstart,
                        float* hout, ushort* __restrict__ gws){
  int d = blockIdx.z*256 + threadIdx.x;
  int c = blockIdx.x, b = blockIdx.y;
  size_t base = ((size_t)(b*TLEN + c*CHUNK))*D_HID + d;
  float h = hstart[((size_t)(b*NCHUNK+c))*D_HID + d];
  #pragma unroll 4
  for (int t=0;t<CHUNK;t++){
    float a  = aw[base + (size_t)t*D_HID];
    float bb = bw[base + (size_t)t*D_HID];
    h = fmaf(a, h, bb);
    hout[base + (size_t)t*D_HID] = h;
    float u = 1.5957691216057308f*(h + 0.044715f*h*h*h);
    float g = h * (1.f/(1.f + __expf(-u)));
    gws[base + (size_t)t*D_HID] = f2bf(g);
  }
}

extern "C" void kernel_launch(void* const* d_in, const int* in_sizes, int n_in,
                              void* d_out, int out_size, void* d_ws, size_t ws_size,
                              hipStream_t stream){
  const float* x      = (const float*)d_in[0];
  const float* h0     = (const float*)d_in[1];
  const float* W_a    = (const float*)d_in[2];
  const float* b_a    = (const float*)d_in[3];
  const float* W_b    = (const float*)d_in[4];
  const float* W_y    = (const float*)d_in[5];
  const float* W_skip = (const float*)d_in[6];
  float* out_h = (float*)d_out;
  float* out_y = out_h + (size_t)M_ROWS*D_HID;

  // Alias big fp32 intermediates onto d_out (read-before-write ordering proven):
  float* aw = out_y;   // 'a' gate values, 128 MiB
  float* bw = out_h;   // 'b' values, 128 MiB

  char* ws = (char*)d_ws;
  ushort* xb    = (ushort*)(ws);                          // 64 MiB
  ushort* gws   = (ushort*)(ws + ((size_t)64<<20));       // 64 MiB
  ushort* WcatT = (ushort*)(ws + ((size_t)128<<20));      // 4 MiB  [2048][1024]
  ushort* W2T   = (ushort*)(ws + ((size_t)132<<20));      // 4 MiB  [1024][2048]
  float*  stA   = (float*)(ws + ((size_t)136<<20));       // 1 MiB
  float*  stB   = (float*)(ws + ((size_t)137<<20));       // 1 MiB
  float*  hstart= (float*)(ws + ((size_t)138<<20));       // 1 MiB

  // allow 128 KiB dynamic LDS for the GEMMs (gfx950: 160 KB/WG max)
  (void)hipFuncSetAttribute((const void*)&k_gemm<1>,
        hipFuncAttributeMaxDynamicSharedMemorySize, 131072);
  (void)hipFuncSetAttribute((const void*)&k_gemm<2>,
        hipFuncAttributeMaxDynamicSharedMemorySize, 131072);

  // x -> bf16
  k_cvt<<<dim3(M_ROWS*D_HID/4/256), 256, 0, stream>>>(x, xb, M_ROWS*D_HID/4);
  // weights -> transposed bf16
  k_tr4<<<dim3(32,32,4), dim3(32,8), 0, stream>>>(
      W_a, W_b, W_y, W_skip,
      WcatT, WcatT + (size_t)1024*1024, W2T, W2T + 1024);
  // GEMM1: [a|b] = x @ [W_a|W_b], sigmoid fused for a   (M=32768, N=2048, K=1024)
  k_gemm<1><<<dim3(8,128), 512, 131072, stream>>>(xb, nullptr, WcatT, 1024, 1024, b_a, aw, bw);
  // chunked scan
  k_scanA<<<dim3(NCHUNK,BATCH,4), 256, 0, stream>>>(aw, bw, stA, stB);
  k_scanB<<<dim3(32), 256, 0, stream>>>(h0, stA, stB, hstart);
  k_scanC<<<dim3(NCHUNK,BATCH,4), 256, 0, stream>>>(aw, bw, hstart, out_h, gws);
  // GEMM2: y = gelu(h) @ W_y + x @ W_skip   (M=32768, N=1024, K=2048 concat)
  k_gemm<2><<<dim3(4,128), 512, 131072, stream>>>(gws, xb, W2T, 2048, 2048, nullptr, out_y, nullptr);
}